// Round 3
// baseline (2155.796 us; speedup 1.0000x reference)
//
#include <hip/hip_runtime.h>
#include <hip/hip_bf16.h>
#include <math.h>

#define HIDDEN 256
#define NPTS 8192
#define NMID_L 9
#define NU_C 0.01f

// softplus100 value + first three derivatives
__device__ __forceinline__ void act_derivs(float z, float& h, float& s1, float& s2, float& s3)
{
    float t = 100.0f * z;
    float s, sp;
    if (t >= 0.0f) {
        float e = __expf(-t);
        s = 1.0f / (1.0f + e);
        sp = t + log1pf(e);
    } else {
        float e = __expf(t);
        s = e / (1.0f + e);
        sp = log1pf(e);
    }
    h  = 0.01f * sp;          // softplus(100z)/100
    s1 = s;                   // sigmoid(100z)
    s2 = 100.0f * s * (1.0f - s);
    s3 = s2 * (100.0f - 200.0f * s);
}

// Layer 0: input (x,y) -> 256, plus jet initialization.
// Pre-activation a = x*W0[0][j] + y*W0[1][j] + b0[j]; a_x = W0[0][j], a_y = W0[1][j],
// all higher pre-activation derivatives are zero.
template<int C>
__global__ void jet_init(const float* __restrict__ x, const float* __restrict__ y,
                         const float* __restrict__ W0, const float* __restrict__ b0,
                         float* __restrict__ J, int n0, int nc)
{
    int idx = blockIdx.x * blockDim.x + threadIdx.x;
    if (idx >= nc * HIDDEN) return;
    int p = idx >> 8;
    int j = idx & 255;
    int gp = n0 + p;
    float ax = W0[j];
    float ay = W0[HIDDEN + j];
    float a = x[gp] * ax + y[gp] * ay + b0[j];
    float h, s1, s2, s3;
    act_derivs(a, h, s1, s2, s3);
    size_t PL = (size_t)nc * HIDDEN;
    size_t base = (size_t)p * HIDDEN + j;
    J[0 * PL + base] = h;
    J[1 * PL + base] = s1 * ax;
    J[2 * PL + base] = s1 * ay;
    if constexpr (C == 10) {
        J[3 * PL + base] = s2 * ax * ax;
        J[4 * PL + base] = s2 * ax * ay;
        J[5 * PL + base] = s2 * ay * ay;
        J[6 * PL + base] = s3 * ax * ax * ax;
        J[7 * PL + base] = s3 * ax * ax * ay;
        J[8 * PL + base] = s3 * ax * ay * ay;
        J[9 * PL + base] = s3 * ay * ay * ay;
    }
}

// One hidden layer: jets_out = chain_rule( jets_in @ W + b ).
// Block: 256 threads = 4 points x 64 lanes; lane owns 4 consecutive output cols.
template<int C>
__global__ __launch_bounds__(256) void jet_layer(
    const float* __restrict__ Jin, const float* __restrict__ W,
    const float* __restrict__ b, float* __restrict__ Jout, int nc)
{
    constexpr int PT = 4;
    __shared__ float lds[C][PT][HIDDEN];
    const int t = threadIdx.x;
    const int p0 = blockIdx.x * PT;
    const size_t PL = (size_t)nc * HIDDEN;

    // Stage all C jet planes of our 4 points into LDS (coalesced float4).
    constexpr int TOT4 = C * PT * (HIDDEN / 4);
    #pragma unroll
    for (int i = 0; i < (TOT4 + 255) / 256; ++i) {
        int id = i * 256 + t;
        if (id < TOT4) {
            int c   = id / (PT * 64);
            int rem = id % (PT * 64);
            int p   = rem >> 6;
            int k4  = rem & 63;
            float4 v = reinterpret_cast<const float4*>(Jin + c * PL + (size_t)(p0 + p) * HIDDEN)[k4];
            reinterpret_cast<float4*>(&lds[c][p][0])[k4] = v;
        }
    }
    __syncthreads();

    const int lane = t & 63;
    const int pg = t >> 6;

    float acc[C][4];
    #pragma unroll
    for (int c = 0; c < C; ++c) {
        acc[c][0] = 0.f; acc[c][1] = 0.f; acc[c][2] = 0.f; acc[c][3] = 0.f;
    }

    const float4* Wv = reinterpret_cast<const float4*>(W);
    for (int k4 = 0; k4 < HIDDEN / 4; ++k4) {
        float4 jv[C];
        #pragma unroll
        for (int c = 0; c < C; ++c)
            jv[c] = reinterpret_cast<const float4*>(&lds[c][pg][0])[k4];
        #pragma unroll
        for (int kk = 0; kk < 4; ++kk) {
            float4 w = Wv[(k4 * 4 + kk) * (HIDDEN / 4) + lane];
            #pragma unroll
            for (int c = 0; c < C; ++c) {
                float jvv = (&jv[c].x)[kk];
                acc[c][0] = fmaf(jvv, w.x, acc[c][0]);
                acc[c][1] = fmaf(jvv, w.y, acc[c][1]);
                acc[c][2] = fmaf(jvv, w.z, acc[c][2]);
                acc[c][3] = fmaf(jvv, w.w, acc[c][3]);
            }
        }
    }

    // Epilogue: chain rule per output unit.
    float4 bv = reinterpret_cast<const float4*>(b)[lane];
    float outv[C][4];
    #pragma unroll
    for (int i = 0; i < 4; ++i) {
        float z = acc[0][i] + (&bv.x)[i];
        float h, s1, s2, s3;
        act_derivs(z, h, s1, s2, s3);
        float ax = acc[1][i], ay = acc[2][i];
        outv[0][i] = h;
        outv[1][i] = s1 * ax;
        outv[2][i] = s1 * ay;
        if constexpr (C == 10) {
            float axx = acc[3][i], axy = acc[4][i], ayy = acc[5][i];
            float axxx = acc[6][i], axxy = acc[7][i], axyy = acc[8][i], ayyy = acc[9][i];
            outv[3][i] = s2 * ax * ax + s1 * axx;
            outv[4][i] = s2 * ax * ay + s1 * axy;
            outv[5][i] = s2 * ay * ay + s1 * ayy;
            outv[6][i] = s3 * ax * ax * ax + 3.f * s2 * ax * axx + s1 * axxx;
            outv[7][i] = s3 * ax * ax * ay + s2 * (2.f * ax * axy + ay * axx) + s1 * axxy;
            outv[8][i] = s3 * ax * ay * ay + s2 * (2.f * ay * axy + ax * ayy) + s1 * axyy;
            outv[9][i] = s3 * ay * ay * ay + 3.f * s2 * ay * ayy + s1 * ayyy;
        }
    }
    #pragma unroll
    for (int c = 0; c < C; ++c) {
        float4 o = make_float4(outv[c][0], outv[c][1], outv[c][2], outv[c][3]);
        reinterpret_cast<float4*>(Jout + c * PL + (size_t)(p0 + pg) * HIDDEN)[lane] = o;
    }
}

// Final linear layer dot products (psi net: 9 derivative components).
__global__ void dots_psi(const float* __restrict__ J, const float* __restrict__ Wl,
                         float* __restrict__ P, int n0, int nc)
{
    int lane = threadIdx.x & 63;
    int p = blockIdx.x * 4 + (threadIdx.x >> 6);
    size_t PL = (size_t)nc * HIDDEN;
    float4 wl = reinterpret_cast<const float4*>(Wl)[lane];
    #pragma unroll
    for (int c = 1; c < 10; ++c) {
        float4 jv = reinterpret_cast<const float4*>(J + c * PL + (size_t)p * HIDDEN)[lane];
        float s = jv.x * wl.x + jv.y * wl.y + jv.z * wl.z + jv.w * wl.w;
        #pragma unroll
        for (int off = 32; off; off >>= 1) s += __shfl_down(s, off, 64);
        if (lane == 0) P[(size_t)(n0 + p) * 16 + (c - 1)] = s;
    }
}

// Final linear layer for p net: value (+bl) and gradient.
__global__ void dots_p(const float* __restrict__ J, const float* __restrict__ Wl,
                       const float* __restrict__ bl,
                       float* __restrict__ P, int n0, int nc)
{
    int lane = threadIdx.x & 63;
    int p = blockIdx.x * 4 + (threadIdx.x >> 6);
    size_t PL = (size_t)nc * HIDDEN;
    float4 wl = reinterpret_cast<const float4*>(Wl)[lane];
    #pragma unroll
    for (int c = 0; c < 3; ++c) {
        float4 jv = reinterpret_cast<const float4*>(J + c * PL + (size_t)p * HIDDEN)[lane];
        float s = jv.x * wl.x + jv.y * wl.y + jv.z * wl.z + jv.w * wl.w;
        #pragma unroll
        for (int off = 32; off; off >>= 1) s += __shfl_down(s, off, 64);
        if (lane == 0) P[(size_t)(n0 + p) * 16 + 9 + c] = s + (c == 0 ? bl[0] : 0.f);
    }
}

// Per-point residuals + block-level partial sums of the 9 reduction terms.
__global__ __launch_bounds__(256) void loss_partials(
    const float* __restrict__ P, const float* __restrict__ u,
    const float* __restrict__ v, const float* __restrict__ pr,
    const int* __restrict__ mask, float* __restrict__ partials)
{
    int i = blockIdx.x * 256 + threadIdx.x;
    float s[9];
    #pragma unroll
    for (int k = 0; k < 9; ++k) s[k] = 0.f;
    if (i < NPTS) {
        const float* Pi = P + (size_t)i * 16;
        float psix = Pi[0], psiy = Pi[1], psixx = Pi[2], psixy = Pi[3], psiyy = Pi[4];
        float psixxx = Pi[5], psixxy = Pi[6], psixyy = Pi[7], psiyyy = Pi[8];
        float pv = Pi[9], ppx = Pi[10], ppy = Pi[11];
        float up = psiy, vp = -psix;
        float u_x = psixy, u_y = psiyy, v_x = -psixx, v_y = -psixy;
        float u_xx = psixxy, u_yy = psiyyy, v_xx = -psixxx, v_yy = -psixyy;
        float f_u = 2.f * up * u_x + up * v_y + vp * u_y + ppx - NU_C * (u_xx + u_yy);
        float f_v = 2.f * vp * v_y + up * v_x + vp * u_x + ppy - NU_C * (v_xx + v_yy);
        float ut = u[i], vt = v[i], pt = pr[i];
        float m = mask[i] ? 1.f : 0.f;
        float du = ut - up, dv = vt - vp, dp = pt - pv;
        s[0] = m * du * du; s[1] = m * dv * dv; s[2] = m * dp * dp;
        s[3] = du * du;     s[4] = dv * dv;     s[5] = dp * dp;
        s[6] = f_u * f_u;   s[7] = f_v * f_v;   s[8] = m;
    }
    int lane = threadIdx.x & 63, wid = threadIdx.x >> 6;
    __shared__ float red[4][9];
    #pragma unroll
    for (int k = 0; k < 9; ++k) {
        float xv = s[k];
        #pragma unroll
        for (int off = 32; off; off >>= 1) xv += __shfl_down(xv, off, 64);
        s[k] = xv;
    }
    if (lane == 0) {
        #pragma unroll
        for (int k = 0; k < 9; ++k) red[wid][k] = s[k];
    }
    __syncthreads();
    if (threadIdx.x == 0) {
        #pragma unroll
        for (int k = 0; k < 9; ++k)
            partials[blockIdx.x * 9 + k] = red[0][k] + red[1][k] + red[2][k] + red[3][k];
    }
}

__global__ void loss_final(const float* __restrict__ partials, float* __restrict__ out)
{
    int lane = threadIdx.x;  // 64 threads, 32 partial rows
    float sums[9];
    #pragma unroll
    for (int k = 0; k < 9; ++k) {
        float xv = (lane < 32) ? partials[lane * 9 + k] : 0.f;
        #pragma unroll
        for (int off = 32; off; off >>= 1) xv += __shfl_down(xv, off, 64);
        sums[k] = xv;
    }
    if (lane == 0) {
        float ms = fmaxf(sums[8], 1.0f);
        float inv_n = 1.0f / (float)NPTS;
        float u_bc = sums[0] / ms, v_bc = sums[1] / ms, p_bc = sums[2] / ms;
        float u_tr = sums[3] * inv_n, v_tr = sums[4] * inv_n, p_tr = sums[5] * inv_n;
        float rans = sums[6] * inv_n + sums[7] * inv_n;
        out[0] = u_bc + v_bc + rans;
        out[1] = p_bc + rans;
        out[2] = u_tr;
        out[3] = v_tr;
        out[4] = p_tr;
        out[5] = rans;
    }
}

extern "C" void kernel_launch(void* const* d_in, const int* in_sizes, int n_in,
                              void* d_out, int out_size, void* d_ws, size_t ws_size,
                              hipStream_t stream)
{
    (void)in_sizes; (void)n_in; (void)out_size;
    const float* x    = (const float*)d_in[0];
    const float* y    = (const float*)d_in[1];
    const float* u    = (const float*)d_in[2];
    const float* v    = (const float*)d_in[3];
    const float* pr   = (const float*)d_in[4];
    const int*   mask = (const int*)d_in[5];
    const float* psi_W0 = (const float*)d_in[6];
    const float* psi_b0 = (const float*)d_in[7];
    const float* psi_Wm = (const float*)d_in[8];
    const float* psi_bm = (const float*)d_in[9];
    const float* psi_Wl = (const float*)d_in[10];
    // d_in[11] = psi_bl: unused (psi value never enters the loss)
    const float* p_W0 = (const float*)d_in[12];
    const float* p_b0 = (const float*)d_in[13];
    const float* p_Wm = (const float*)d_in[14];
    const float* p_bm = (const float*)d_in[15];
    const float* p_Wl = (const float*)d_in[16];
    const float* p_bl = (const float*)d_in[17];

    float* P        = (float*)d_ws;            // NPTS*16 per-point scalars
    float* partials = P + (size_t)NPTS * 16;   // 32*9 partial sums (padded to 512)
    float* jets     = partials + 512;

    size_t head_bytes = ((size_t)NPTS * 16 + 512) * sizeof(float);
    size_t avail = (ws_size > head_bytes) ? (ws_size - head_bytes) : 0;
    int nc = NPTS;
    while (nc > 256 && (size_t)2 * 10 * nc * HIDDEN * sizeof(float) > avail) nc >>= 1;

    size_t planes10 = (size_t)10 * nc * HIDDEN;
    float* bufA = jets;
    float* bufB = jets + planes10;

    for (int n0 = 0; n0 < NPTS; n0 += nc) {
        // --- psi net: 10 jet components ---
        jet_init<10><<<(nc * HIDDEN) / 256, 256, 0, stream>>>(x, y, psi_W0, psi_b0, bufA, n0, nc);
        float* cur = bufA; float* nxt = bufB;
        for (int l = 0; l < NMID_L; ++l) {
            jet_layer<10><<<nc / 4, 256, 0, stream>>>(
                cur, psi_Wm + (size_t)l * HIDDEN * HIDDEN, psi_bm + (size_t)l * HIDDEN, nxt, nc);
            float* tmp = cur; cur = nxt; nxt = tmp;
        }
        dots_psi<<<nc / 4, 256, 0, stream>>>(cur, psi_Wl, P, n0, nc);

        // --- p net: 3 jet components ---
        jet_init<3><<<(nc * HIDDEN) / 256, 256, 0, stream>>>(x, y, p_W0, p_b0, bufA, n0, nc);
        cur = bufA; nxt = bufB;
        for (int l = 0; l < NMID_L; ++l) {
            jet_layer<3><<<nc / 4, 256, 0, stream>>>(
                cur, p_Wm + (size_t)l * HIDDEN * HIDDEN, p_bm + (size_t)l * HIDDEN, nxt, nc);
            float* tmp = cur; cur = nxt; nxt = tmp;
        }
        dots_p<<<nc / 4, 256, 0, stream>>>(cur, p_Wl, p_bl, P, n0, nc);
    }

    loss_partials<<<NPTS / 256, 256, 0, stream>>>(P, u, v, pr, mask, partials);
    loss_final<<<1, 64, 0, stream>>>(partials, (float*)d_out);
}